// Round 1
// baseline (63.334 us; speedup 1.0000x reference)
//
#include <hip/hip_runtime.h>
#include <hip/hip_bf16.h>

// GRU cell: B=16384, IN=256, UNITS=256, K = IN+UNITS = 512.
//   z = sigmoid([h,x]@Wz + bz); r = sigmoid([h,x]@Wr + br)
//   h~ = tanh([r*h, x]@Ws + bs);  h' = (1-z)*h + z*h~
// Strategy: bf16 MFMA (16x16x32). Weights pre-packed to B-fragment layout in ws.
// One block owns 64 rows; LDS holds the 64x512 bf16 concat tile (XOR-swizzled).

#define BATCH 16384
#define UNITS 256
#define KDIM 512

typedef float f32x4 __attribute__((ext_vector_type(4)));
typedef __bf16 bf16x8 __attribute__((ext_vector_type(8)));
typedef unsigned short us8 __attribute__((ext_vector_type(8)));
typedef unsigned short us4v __attribute__((ext_vector_type(4)));

static __device__ __forceinline__ unsigned short f2bf(float f) {
    union { float f; unsigned u; } v; v.f = f;
    unsigned r = v.u + 0x7fffu + ((v.u >> 16) & 1u);   // RNE
    return (unsigned short)(r >> 16);
}

// Pack W[512][256] (row-major fp32) -> frag layout [kt][nt][lane][8] bf16.
// lane l covers col nt*16 + (l&15), k = kt*32 + (l>>4)*8 + j  (j=0..7).
__global__ void pack_weights(const float* __restrict__ Wz,
                             const float* __restrict__ Wr,
                             const float* __restrict__ Ws,
                             unsigned short* __restrict__ out) {
    int gid = blockIdx.x * blockDim.x + threadIdx.x;   // 0 .. 3*131072
    int w   = gid >> 17;
    int rem = gid & 131071;
    int k = rem >> 8;
    int n = rem & 255;
    const float* W = (w == 0) ? Wz : (w == 1) ? Wr : Ws;
    float f = W[rem];                                  // coalesced read
    int kt = k >> 5, kr = k & 31;
    int hi = kr >> 3, j = kr & 7;
    int nt = n >> 4,  lo = n & 15;
    int l  = hi * 16 + lo;
    out[(size_t)w * 131072 + (size_t)(((kt * 16 + nt) * 64 + l) * 8 + j)] = f2bf(f);
}

__launch_bounds__(512, 2)
__global__ void gru_main(const float* __restrict__ x,
                         const float* __restrict__ ph,
                         const float* __restrict__ bz,
                         const float* __restrict__ br,
                         const float* __restrict__ bs,
                         const unsigned short* __restrict__ Wp,
                         float* __restrict__ out) {
    __shared__ unsigned short sm[64 * 512];            // 64 KiB, rows XOR-swizzled

    const int tid  = threadIdx.x;
    const int lane = tid & 63;
    const int wid  = tid >> 6;                         // 0..7
    const int mw   = wid >> 1;                         // 0..3  (M split)
    const int nw   = wid & 1;                          // 0..1  (N split)
    const int brow = blockIdx.x * 64;

    // ---- load prev_h -> k[0,256), x -> k[256,512) as bf16, swizzled ----
    for (int i = tid; i < 4096; i += 512) {            // 4096 float4 per matrix
        int row = i >> 6;
        int c4  = (i & 63) << 2;
        int swr = (row & 7) << 3;
        float4 a = *(const float4*)&ph[(size_t)(brow + row) * 256 + c4];
        us4v u; u.x = f2bf(a.x); u.y = f2bf(a.y); u.z = f2bf(a.z); u.w = f2bf(a.w);
        *(us4v*)&sm[row * 512 + (c4 ^ swr)] = u;
        float4 b = *(const float4*)&x[(size_t)(brow + row) * 256 + c4];
        us4v v; v.x = f2bf(b.x); v.y = f2bf(b.y); v.z = f2bf(b.z); v.w = f2bf(b.w);
        *(us4v*)&sm[row * 512 + ((256 + c4) ^ swr)] = v;
    }
    __syncthreads();

    const unsigned short* Wz_p = Wp;                   // [16][16][64][8]
    const unsigned short* Wr_p = Wp + 131072;
    const unsigned short* Ws_p = Wp + 262144;

    const int lr_base = mw * 16;
    const int arow    = lr_base + (lane & 15);         // A-frag row (local)
    const int asw     = (arow & 7) << 3;
    const int kg      = (lane >> 4) << 3;              // k sub-offset 0,8,16,24

    // ---- stage 1: z and r GEMMs share the A fragment ----
    f32x4 accz[8] = {};
    f32x4 accr[8] = {};
    for (int kt = 0; kt < 16; ++kt) {
        int ak = kt * 32 + kg;
        bf16x8 a = __builtin_bit_cast(bf16x8, *(const us8*)&sm[arow * 512 + (ak ^ asw)]);
        const unsigned short* bzp = Wz_p + (size_t)(((kt * 16 + nw * 8) * 64 + lane) * 8);
        const unsigned short* brp = Wr_p + (size_t)(((kt * 16 + nw * 8) * 64 + lane) * 8);
#pragma unroll
        for (int t = 0; t < 8; ++t) {
            bf16x8 b0 = __builtin_bit_cast(bf16x8, *(const us8*)(bzp + t * 512));
            accz[t] = __builtin_amdgcn_mfma_f32_16x16x32_bf16(a, b0, accz[t], 0, 0, 0);
            bf16x8 b1 = __builtin_bit_cast(bf16x8, *(const us8*)(brp + t * 512));
            accr[t] = __builtin_amdgcn_mfma_f32_16x16x32_bf16(a, b1, accr[t], 0, 0, 0);
        }
    }
    __syncthreads();   // everyone done reading the prev_h half

    // ---- z=sigmoid, r=sigmoid, write rh=r*prev_h back over k[0,256) ----
    const int colbase = nw * 128 + (lane & 15);
    const int rrow0   = (lane >> 4) * 4;
#pragma unroll
    for (int t = 0; t < 8; ++t) {
        int col = colbase + t * 16;
        float bzc = bz[col], brc = br[col];
#pragma unroll
        for (int i = 0; i < 4; ++i) {
            float z = 1.f / (1.f + __expf(-(accz[t][i] + bzc)));
            accz[t][i] = z;                             // keep z for epilogue
            float r = 1.f / (1.f + __expf(-(accr[t][i] + brc)));
            int lrow = lr_base + rrow0 + i;
            int grow = brow + lrow;
            float rh = r * ph[(size_t)grow * 256 + col];
            sm[lrow * 512 + (col ^ ((lrow & 7) << 3))] = f2bf(rh);
        }
    }
    __syncthreads();

    // ---- stage 2: candidate GEMM over [rh, x] ----
    f32x4 accs[8] = {};
    for (int kt = 0; kt < 16; ++kt) {
        int ak = kt * 32 + kg;
        bf16x8 a = __builtin_bit_cast(bf16x8, *(const us8*)&sm[arow * 512 + (ak ^ asw)]);
        const unsigned short* bsp = Ws_p + (size_t)(((kt * 16 + nw * 8) * 64 + lane) * 8);
#pragma unroll
        for (int t = 0; t < 8; ++t) {
            bf16x8 b = __builtin_bit_cast(bf16x8, *(const us8*)(bsp + t * 512));
            accs[t] = __builtin_amdgcn_mfma_f32_16x16x32_bf16(a, b, accs[t], 0, 0, 0);
        }
    }

    // ---- epilogue: h' = (1-z)*h + z*tanh(s+bs) ----
#pragma unroll
    for (int t = 0; t < 8; ++t) {
        int col = colbase + t * 16;
        float bsc = bs[col];
#pragma unroll
        for (int i = 0; i < 4; ++i) {
            float s = accs[t][i] + bsc;
            float e = __expf(-2.f * fabsf(s));
            float th = (1.f - e) / (1.f + e);
            th = (s < 0.f) ? -th : th;
            float z = accz[t][i];
            int grow = brow + lr_base + rrow0 + i;
            float p = ph[(size_t)grow * 256 + col];
            out[(size_t)grow * 256 + col] = (1.f - z) * p + z * th;
        }
    }
}

extern "C" void kernel_launch(void* const* d_in, const int* in_sizes, int n_in,
                              void* d_out, int out_size, void* d_ws, size_t ws_size,
                              hipStream_t stream) {
    const float* x  = (const float*)d_in[0];
    const float* ph = (const float*)d_in[1];
    const float* Wz = (const float*)d_in[2];
    const float* bz = (const float*)d_in[3];
    const float* Wr = (const float*)d_in[4];
    const float* br = (const float*)d_in[5];
    const float* Ws = (const float*)d_in[6];
    const float* bs = (const float*)d_in[7];
    unsigned short* Wp = (unsigned short*)d_ws;        // 786432 bytes used

    hipLaunchKernelGGL(pack_weights, dim3(1536), dim3(256), 0, stream, Wz, Wr, Ws, Wp);
    hipLaunchKernelGGL(gru_main, dim3(256), dim3(512), 0, stream,
                       x, ph, bz, br, bs, Wp, (float*)d_out);
}

// Round 6
// 39.256 us; speedup vs baseline: 1.6134x; 1.6134x over previous
//
#include <hip/hip_runtime.h>
#include <hip/hip_bf16.h>

// GRU cell: B=16384, IN=256, UNITS=256, K = IN+UNITS = 512.
//   z = sigmoid([h,x]@Wz + bz); r = sigmoid([h,x]@Wr + br)
//   h~ = tanh([r*h, x]@Ws + bs);  h' = (1-z)*h + z*h~
// Round 2 kernel (resubmit #4 after repeated infra failures): 32-row tiles
// (grid 512, 2 blocks/CU), 8 waves each owning 32 rows x 32 cols (no
// intra-block weight redundancy), ph reused from LDS.

#define BATCH 16384
#define UNITS 256
#define KDIM 512
#define ROWS 32

typedef float f32x4 __attribute__((ext_vector_type(4)));
typedef __bf16 bf16x8 __attribute__((ext_vector_type(8)));
typedef unsigned short us8 __attribute__((ext_vector_type(8)));
typedef unsigned short us4v __attribute__((ext_vector_type(4)));

static __device__ __forceinline__ unsigned short f2bf(float f) {
    union { float f; unsigned u; } v; v.f = f;
    unsigned r = v.u + 0x7fffu + ((v.u >> 16) & 1u);   // RNE
    return (unsigned short)(r >> 16);
}
static __device__ __forceinline__ float bf2f(unsigned short u) {
    union { unsigned u; float f; } v; v.u = ((unsigned)u) << 16;
    return v.f;
}

// Pack W[512][256] (row-major fp32) -> frag layout [kt][nt][lane][8] bf16.
// lane l covers col nt*16 + (l&15), k = kt*32 + (l>>4)*8 + j  (j=0..7).
__global__ void pack_weights(const float* __restrict__ Wz,
                             const float* __restrict__ Wr,
                             const float* __restrict__ Ws,
                             unsigned short* __restrict__ out) {
    int gid = blockIdx.x * blockDim.x + threadIdx.x;   // 0 .. 3*131072
    int w   = gid >> 17;
    int rem = gid & 131071;
    int k = rem >> 8;
    int n = rem & 255;
    const float* W = (w == 0) ? Wz : (w == 1) ? Wr : Ws;
    float f = W[rem];                                  // coalesced read
    int kt = k >> 5, kr = k & 31;
    int hi = kr >> 3, j = kr & 7;
    int nt = n >> 4,  lo = n & 15;
    int l  = hi * 16 + lo;
    out[(size_t)w * 131072 + (size_t)(((kt * 16 + nt) * 64 + l) * 8 + j)] = f2bf(f);
}

__launch_bounds__(512, 4)
__global__ void gru_main(const float* __restrict__ x,
                         const float* __restrict__ ph,
                         const float* __restrict__ bz,
                         const float* __restrict__ br,
                         const float* __restrict__ bs,
                         const unsigned short* __restrict__ Wp,
                         float* __restrict__ out) {
    __shared__ unsigned short sm[ROWS * 512];          // 32 KiB, XOR-swizzled rows

    const int tid  = threadIdx.x;
    const int lane = tid & 63;
    const int wid  = tid >> 6;                         // 0..7 = N-slice owner
    const int brow = blockIdx.x * ROWS;

    // ---- load prev_h -> k[0,256), x -> k[256,512) as bf16, swizzled ----
    for (int i = tid; i < 2048; i += 512) {            // 2048 float4 per matrix
        int row = i >> 6;                              // 0..31
        int c4  = (i & 63) << 2;
        int swr = (row & 7) << 3;
        float4 a = *(const float4*)&ph[(size_t)(brow + row) * 256 + c4];
        us4v u; u.x = f2bf(a.x); u.y = f2bf(a.y); u.z = f2bf(a.z); u.w = f2bf(a.w);
        *(us4v*)&sm[row * 512 + (c4 ^ swr)] = u;
        float4 b = *(const float4*)&x[(size_t)(brow + row) * 256 + c4];
        us4v v; v.x = f2bf(b.x); v.y = f2bf(b.y); v.z = f2bf(b.z); v.w = f2bf(b.w);
        *(us4v*)&sm[row * 512 + ((256 + c4) ^ swr)] = v;
    }
    __syncthreads();

    const unsigned short* Wz_p = Wp;                   // [16][16][64][8]
    const unsigned short* Wr_p = Wp + 131072;
    const unsigned short* Ws_p = Wp + 262144;

    const int l15 = lane & 15;
    const int kg  = (lane >> 4) << 3;                  // k sub-offset 0,8,16,24

    // ---- stage 1: z and r GEMMs; wave owns cols [wid*32, wid*32+32) ----
    f32x4 accz[2][2] = {};
    f32x4 accr[2][2] = {};
    for (int kt = 0; kt < 16; ++kt) {
        int ak = kt * 32 + kg;
        bf16x8 a[2];
#pragma unroll
        for (int m = 0; m < 2; ++m) {
            int arow = m * 16 + l15;
            a[m] = __builtin_bit_cast(bf16x8,
                *(const us8*)&sm[arow * 512 + (ak ^ ((arow & 7) << 3))]);
        }
#pragma unroll
        for (int t = 0; t < 2; ++t) {
            int nt = wid * 2 + t;
            size_t bidx = (size_t)(((kt * 16 + nt) * 64 + lane) * 8);
            bf16x8 b0 = __builtin_bit_cast(bf16x8, *(const us8*)(Wz_p + bidx));
            bf16x8 b1 = __builtin_bit_cast(bf16x8, *(const us8*)(Wr_p + bidx));
#pragma unroll
            for (int m = 0; m < 2; ++m) {
                accz[m][t] = __builtin_amdgcn_mfma_f32_16x16x32_bf16(a[m], b0, accz[m][t], 0, 0, 0);
                accr[m][t] = __builtin_amdgcn_mfma_f32_16x16x32_bf16(a[m], b1, accr[m][t], 0, 0, 0);
            }
        }
    }
    __syncthreads();   // all waves done reading A-frags (incl. prev_h half)

    // ---- z=sigmoid, r=sigmoid; rh=r*ph overwrites k[0,256); stash p,z ----
    float pst[2][2][4];
    const int rrow0 = (lane >> 4) * 4;
#pragma unroll
    for (int t = 0; t < 2; ++t) {
        int col = wid * 32 + t * 16 + l15;
        float bzc = bz[col], brc = br[col];
#pragma unroll
        for (int m = 0; m < 2; ++m) {
#pragma unroll
            for (int i = 0; i < 4; ++i) {
                int lrow = m * 16 + rrow0 + i;
                int addr = lrow * 512 + (col ^ ((lrow & 7) << 3));
                float p = bf2f(sm[addr]);              // prev_h (bf16) from LDS
                float z = 1.f / (1.f + __expf(-(accz[m][t][i] + bzc)));
                float r = 1.f / (1.f + __expf(-(accr[m][t][i] + brc)));
                accz[m][t][i] = z;                     // keep z for epilogue
                pst[m][t][i]  = p;                     // keep p for epilogue
                sm[addr] = f2bf(r * p);                // rh in place (1 owner/elem)
            }
        }
    }
    __syncthreads();

    // ---- stage 2: candidate GEMM over [rh, x] ----
    f32x4 accs[2][2] = {};
    for (int kt = 0; kt < 16; ++kt) {
        int ak = kt * 32 + kg;
        bf16x8 a[2];
#pragma unroll
        for (int m = 0; m < 2; ++m) {
            int arow = m * 16 + l15;
            a[m] = __builtin_bit_cast(bf16x8,
                *(const us8*)&sm[arow * 512 + (ak ^ ((arow & 7) << 3))]);
        }
#pragma unroll
        for (int t = 0; t < 2; ++t) {
            int nt = wid * 2 + t;
            size_t bidx = (size_t)(((kt * 16 + nt) * 64 + lane) * 8);
            bf16x8 b = __builtin_bit_cast(bf16x8, *(const us8*)(Ws_p + bidx));
#pragma unroll
            for (int m = 0; m < 2; ++m) {
                accs[m][t] = __builtin_amdgcn_mfma_f32_16x16x32_bf16(a[m], b, accs[m][t], 0, 0, 0);
            }
        }
    }

    // ---- epilogue: h' = (1-z)*p + z*tanh(s+bs) ----
#pragma unroll
    for (int t = 0; t < 2; ++t) {
        int col = wid * 32 + t * 16 + l15;
        float bsc = bs[col];
#pragma unroll
        for (int m = 0; m < 2; ++m) {
#pragma unroll
            for (int i = 0; i < 4; ++i) {
                float s = accs[m][t][i] + bsc;
                float e = __expf(-2.f * fabsf(s));
                float th = (1.f - e) / (1.f + e);
                th = (s < 0.f) ? -th : th;
                float z = accz[m][t][i];
                float p = pst[m][t][i];
                int grow = brow + m * 16 + rrow0 + i;
                out[(size_t)grow * 256 + col] = (1.f - z) * p + z * th;
            }
        }
    }
}

extern "C" void kernel_launch(void* const* d_in, const int* in_sizes, int n_in,
                              void* d_out, int out_size, void* d_ws, size_t ws_size,
                              hipStream_t stream) {
    const float* x  = (const float*)d_in[0];
    const float* ph = (const float*)d_in[1];
    const float* Wz = (const float*)d_in[2];
    const float* bz = (const float*)d_in[3];
    const float* Wr = (const float*)d_in[4];
    const float* br = (const float*)d_in[5];
    const float* Ws = (const float*)d_in[6];
    const float* bs = (const float*)d_in[7];
    unsigned short* Wp = (unsigned short*)d_ws;        // 786432 bytes used

    hipLaunchKernelGGL(pack_weights, dim3(1536), dim3(256), 0, stream, Wz, Wr, Ws, Wp);
    hipLaunchKernelGGL(gru_main, dim3(512), dim3(512), 0, stream,
                       x, ph, bz, br, bs, Wp, (float*)d_out);
}

// Round 7
// 37.233 us; speedup vs baseline: 1.7010x; 1.0543x over previous
//
#include <hip/hip_runtime.h>
#include <hip/hip_bf16.h>

// GRU cell: B=16384, IN=256, UNITS=256, K = IN+UNITS = 512.
//   z = sigmoid([h,x]@Wz + bz); r = sigmoid([h,x]@Wr + br)
//   h~ = tanh([r*h, x]@Ws + bs);  h' = (1-z)*h + z*h~
// Round 7: 64-row tiles, 1024 threads (16 waves), wave owns 64 rows x 16 cols.
// Grid 256 -> L2 weight traffic halves to 196 MB. 4 waves/SIMD maintained.

#define BATCH 16384
#define UNITS 256
#define KDIM 512
#define ROWS 64

typedef float f32x4 __attribute__((ext_vector_type(4)));
typedef __bf16 bf16x8 __attribute__((ext_vector_type(8)));
typedef unsigned short us8 __attribute__((ext_vector_type(8)));
typedef unsigned short us4v __attribute__((ext_vector_type(4)));

static __device__ __forceinline__ unsigned short f2bf(float f) {
    union { float f; unsigned u; } v; v.f = f;
    unsigned r = v.u + 0x7fffu + ((v.u >> 16) & 1u);   // RNE
    return (unsigned short)(r >> 16);
}
static __device__ __forceinline__ float bf2f(unsigned short u) {
    union { unsigned u; float f; } v; v.u = ((unsigned)u) << 16;
    return v.f;
}

// Pack W[512][256] (row-major fp32) -> frag layout [kt][nt][lane][8] bf16.
// lane l covers col nt*16 + (l&15), k = kt*32 + (l>>4)*8 + j  (j=0..7).
__global__ void pack_weights(const float* __restrict__ Wz,
                             const float* __restrict__ Wr,
                             const float* __restrict__ Ws,
                             unsigned short* __restrict__ out) {
    int gid = blockIdx.x * blockDim.x + threadIdx.x;   // 0 .. 3*131072
    int w   = gid >> 17;
    int rem = gid & 131071;
    int k = rem >> 8;
    int n = rem & 255;
    const float* W = (w == 0) ? Wz : (w == 1) ? Wr : Ws;
    float f = W[rem];                                  // coalesced read
    int kt = k >> 5, kr = k & 31;
    int hi = kr >> 3, j = kr & 7;
    int nt = n >> 4,  lo = n & 15;
    int l  = hi * 16 + lo;
    out[(size_t)w * 131072 + (size_t)(((kt * 16 + nt) * 64 + l) * 8 + j)] = f2bf(f);
}

__launch_bounds__(1024, 4)
__global__ void gru_main(const float* __restrict__ x,
                         const float* __restrict__ ph,
                         const float* __restrict__ bz,
                         const float* __restrict__ br,
                         const float* __restrict__ bs,
                         const unsigned short* __restrict__ Wp,
                         float* __restrict__ out) {
    __shared__ unsigned short sm[ROWS * 512];          // 64 KiB, XOR-swizzled rows

    const int tid  = threadIdx.x;
    const int lane = tid & 63;
    const int wid  = tid >> 6;                         // 0..15 = N-slice owner (nt)
    const int brow = blockIdx.x * ROWS;

    // ---- load prev_h -> k[0,256), x -> k[256,512) as bf16, swizzled ----
    for (int i = tid; i < 4096; i += 1024) {           // 4096 float4 per matrix
        int row = i >> 6;                              // 0..63
        int c4  = (i & 63) << 2;
        int swr = (row & 7) << 3;
        float4 a = *(const float4*)&ph[(size_t)(brow + row) * 256 + c4];
        us4v u; u.x = f2bf(a.x); u.y = f2bf(a.y); u.z = f2bf(a.z); u.w = f2bf(a.w);
        *(us4v*)&sm[row * 512 + (c4 ^ swr)] = u;
        float4 b = *(const float4*)&x[(size_t)(brow + row) * 256 + c4];
        us4v v; v.x = f2bf(b.x); v.y = f2bf(b.y); v.z = f2bf(b.z); v.w = f2bf(b.w);
        *(us4v*)&sm[row * 512 + ((256 + c4) ^ swr)] = v;
    }
    __syncthreads();

    const unsigned short* Wz_p = Wp;                   // [16][16][64][8]
    const unsigned short* Wr_p = Wp + 131072;
    const unsigned short* Ws_p = Wp + 262144;

    const int l15 = lane & 15;
    const int kg  = (lane >> 4) << 3;                  // k sub-offset 0,8,16,24

    // ---- stage 1: z and r GEMMs; wave owns cols [wid*16, wid*16+16) ----
    f32x4 accz[4] = {};
    f32x4 accr[4] = {};
    for (int kt = 0; kt < 16; ++kt) {
        int ak = kt * 32 + kg;
        size_t bidx = (size_t)(((kt * 16 + wid) * 64 + lane) * 8);
        bf16x8 b0 = __builtin_bit_cast(bf16x8, *(const us8*)(Wz_p + bidx));
        bf16x8 b1 = __builtin_bit_cast(bf16x8, *(const us8*)(Wr_p + bidx));
#pragma unroll
        for (int m = 0; m < 4; ++m) {
            int arow = m * 16 + l15;
            bf16x8 a = __builtin_bit_cast(bf16x8,
                *(const us8*)&sm[arow * 512 + (ak ^ ((arow & 7) << 3))]);
            accz[m] = __builtin_amdgcn_mfma_f32_16x16x32_bf16(a, b0, accz[m], 0, 0, 0);
            accr[m] = __builtin_amdgcn_mfma_f32_16x16x32_bf16(a, b1, accr[m], 0, 0, 0);
        }
    }
    __syncthreads();   // all waves done reading A-frags (incl. prev_h half)

    // ---- z=sigmoid, r=sigmoid; rh=r*ph overwrites k[0,256); stash p,z ----
    float pst[4][4];
    const int rrow0 = (lane >> 4) * 4;
    const int col   = wid * 16 + l15;
    {
        float bzc = bz[col], brc = br[col];
#pragma unroll
        for (int m = 0; m < 4; ++m) {
#pragma unroll
            for (int i = 0; i < 4; ++i) {
                int lrow = m * 16 + rrow0 + i;
                int addr = lrow * 512 + (col ^ ((lrow & 7) << 3));
                float p = bf2f(sm[addr]);              // prev_h (bf16) from LDS
                float z = 1.f / (1.f + __expf(-(accz[m][i] + bzc)));
                float r = 1.f / (1.f + __expf(-(accr[m][i] + brc)));
                accz[m][i] = z;                        // keep z for epilogue
                pst[m][i]  = p;                        // keep p for epilogue
                sm[addr] = f2bf(r * p);                // rh in place (1 owner/elem)
            }
        }
    }
    __syncthreads();

    // ---- stage 2: candidate GEMM over [rh, x] ----
    f32x4 accs[4] = {};
    for (int kt = 0; kt < 16; ++kt) {
        int ak = kt * 32 + kg;
        size_t bidx = (size_t)(((kt * 16 + wid) * 64 + lane) * 8);
        bf16x8 b = __builtin_bit_cast(bf16x8, *(const us8*)(Ws_p + bidx));
#pragma unroll
        for (int m = 0; m < 4; ++m) {
            int arow = m * 16 + l15;
            bf16x8 a = __builtin_bit_cast(bf16x8,
                *(const us8*)&sm[arow * 512 + (ak ^ ((arow & 7) << 3))]);
            accs[m] = __builtin_amdgcn_mfma_f32_16x16x32_bf16(a, b, accs[m], 0, 0, 0);
        }
    }

    // ---- epilogue: h' = (1-z)*p + z*tanh(s+bs) ----
    {
        float bsc = bs[col];
#pragma unroll
        for (int m = 0; m < 4; ++m) {
#pragma unroll
            for (int i = 0; i < 4; ++i) {
                float s = accs[m][i] + bsc;
                float e = __expf(-2.f * fabsf(s));
                float th = (1.f - e) / (1.f + e);
                th = (s < 0.f) ? -th : th;
                float z = accz[m][i];
                float p = pst[m][i];
                int grow = brow + m * 16 + rrow0 + i;
                out[(size_t)grow * 256 + col] = (1.f - z) * p + z * th;
            }
        }
    }
}

extern "C" void kernel_launch(void* const* d_in, const int* in_sizes, int n_in,
                              void* d_out, int out_size, void* d_ws, size_t ws_size,
                              hipStream_t stream) {
    const float* x  = (const float*)d_in[0];
    const float* ph = (const float*)d_in[1];
    const float* Wz = (const float*)d_in[2];
    const float* bz = (const float*)d_in[3];
    const float* Wr = (const float*)d_in[4];
    const float* br = (const float*)d_in[5];
    const float* Ws = (const float*)d_in[6];
    const float* bs = (const float*)d_in[7];
    unsigned short* Wp = (unsigned short*)d_ws;        // 786432 bytes used

    hipLaunchKernelGGL(pack_weights, dim3(1536), dim3(256), 0, stream, Wz, Wr, Ws, Wp);
    hipLaunchKernelGGL(gru_main, dim3(256), dim3(1024), 0, stream,
                       x, ph, bz, br, bs, Wp, (float*)d_out);
}

// Round 8
// 34.112 us; speedup vs baseline: 1.8566x; 1.0915x over previous
//
#include <hip/hip_runtime.h>
#include <hip/hip_bf16.h>

// GRU cell: B=16384, IN=256, UNITS=256, K = IN+UNITS = 512.
//   z = sigmoid([h,x]@Wz + bz); r = sigmoid([h,x]@Wr + br)
//   h~ = tanh([r*h, x]@Ws + bs);  h' = (1-z)*h + z*h~
// Round 8: latency attack. Separate rh LDS buffer (drops middle barrier),
// explicit depth-1/2 B-frag prefetch in both GEMM loops, kt=0 weight loads
// issued before staging, Ws prefetch hidden under sigmoid VALU phase.

#define BATCH 16384
#define UNITS 256
#define KDIM 512
#define ROWS 64

typedef float f32x4 __attribute__((ext_vector_type(4)));
typedef __bf16 bf16x8 __attribute__((ext_vector_type(8)));
typedef unsigned short us8 __attribute__((ext_vector_type(8)));
typedef unsigned short us4v __attribute__((ext_vector_type(4)));

static __device__ __forceinline__ unsigned short f2bf(float f) {
    union { float f; unsigned u; } v; v.f = f;
    unsigned r = v.u + 0x7fffu + ((v.u >> 16) & 1u);   // RNE
    return (unsigned short)(r >> 16);
}
static __device__ __forceinline__ float bf2f(unsigned short u) {
    union { unsigned u; float f; } v; v.u = ((unsigned)u) << 16;
    return v.f;
}

// Pack W[512][256] (row-major fp32) -> frag layout [kt][nt][lane][8] bf16.
// lane l covers col nt*16 + (l&15), k = kt*32 + (l>>4)*8 + j  (j=0..7).
__global__ void pack_weights(const float* __restrict__ Wz,
                             const float* __restrict__ Wr,
                             const float* __restrict__ Ws,
                             unsigned short* __restrict__ out) {
    int gid = blockIdx.x * blockDim.x + threadIdx.x;   // 0 .. 3*131072
    int w   = gid >> 17;
    int rem = gid & 131071;
    int k = rem >> 8;
    int n = rem & 255;
    const float* W = (w == 0) ? Wz : (w == 1) ? Wr : Ws;
    float f = W[rem];                                  // coalesced read
    int kt = k >> 5, kr = k & 31;
    int hi = kr >> 3, j = kr & 7;
    int nt = n >> 4,  lo = n & 15;
    int l  = hi * 16 + lo;
    out[(size_t)w * 131072 + (size_t)(((kt * 16 + nt) * 64 + l) * 8 + j)] = f2bf(f);
}

__launch_bounds__(1024, 4)
__global__ void gru_main(const float* __restrict__ x,
                         const float* __restrict__ ph,
                         const float* __restrict__ bz,
                         const float* __restrict__ br,
                         const float* __restrict__ bs,
                         const unsigned short* __restrict__ Wp,
                         float* __restrict__ out) {
    __shared__ unsigned short sm[ROWS * 512];          // 64 KiB: [ph | x], swizzled
    __shared__ unsigned short rh[ROWS * 256];          // 32 KiB: r*ph, swizzled

    const int tid  = threadIdx.x;
    const int lane = tid & 63;
    const int wid  = tid >> 6;                         // 0..15 = N-slice (nt)
    const int brow = blockIdx.x * ROWS;

    const int l15 = lane & 15;
    const int kg  = (lane >> 4) << 3;                  // k sub-offset 0,8,16,24
    const int col = wid * 16 + l15;

    // hoisted: biases + first Wz/Wr frags (independent of LDS staging)
    const unsigned short* Wz_p = Wp;                   // [16][16][64][8]
    const unsigned short* Wr_p = Wp + 131072;
    const unsigned short* Ws_p = Wp + 262144;
    const unsigned short* pz = Wz_p + (size_t)((wid * 64 + lane) * 8);
    const unsigned short* pr = Wr_p + (size_t)((wid * 64 + lane) * 8);
    const unsigned short* ps = Ws_p + (size_t)((wid * 64 + lane) * 8);
    us8 b0n = *(const us8*)pz;                         // kt=0, in flight during staging
    us8 b1n = *(const us8*)pr;
    float bzc = bz[col], brc = br[col], bsc = bs[col];

    // ---- stage ph -> k[0,256), x -> k[256,512) as bf16, swizzled ----
    for (int i = tid; i < 4096; i += 1024) {           // 4096 float4 per matrix
        int row = i >> 6;                              // 0..63
        int c4  = (i & 63) << 2;
        int swr = (row & 7) << 3;
        float4 a = *(const float4*)&ph[(size_t)(brow + row) * 256 + c4];
        us4v u; u.x = f2bf(a.x); u.y = f2bf(a.y); u.z = f2bf(a.z); u.w = f2bf(a.w);
        *(us4v*)&sm[row * 512 + (c4 ^ swr)] = u;
        float4 b = *(const float4*)&x[(size_t)(brow + row) * 256 + c4];
        us4v v; v.x = f2bf(b.x); v.y = f2bf(b.y); v.z = f2bf(b.z); v.w = f2bf(b.w);
        *(us4v*)&sm[row * 512 + ((256 + c4) ^ swr)] = v;
    }
    __syncthreads();

    // ---- stage 1: z and r GEMMs, depth-1 prefetch ----
    f32x4 accz[4] = {};
    f32x4 accr[4] = {};
#pragma unroll 4
    for (int kt = 0; kt < 16; ++kt) {
        bf16x8 B0 = __builtin_bit_cast(bf16x8, b0n);
        bf16x8 B1 = __builtin_bit_cast(bf16x8, b1n);
        if (kt < 15) {
            b0n = *(const us8*)(pz + (size_t)(kt + 1) * 8192);
            b1n = *(const us8*)(pr + (size_t)(kt + 1) * 8192);
        }
        int ak = kt * 32 + kg;
#pragma unroll
        for (int m = 0; m < 4; ++m) {
            int arow = m * 16 + l15;
            bf16x8 a = __builtin_bit_cast(bf16x8,
                *(const us8*)&sm[arow * 512 + (ak ^ ((arow & 7) << 3))]);
            accz[m] = __builtin_amdgcn_mfma_f32_16x16x32_bf16(a, B0, accz[m], 0, 0, 0);
            accr[m] = __builtin_amdgcn_mfma_f32_16x16x32_bf16(a, B1, accr[m], 0, 0, 0);
        }
    }

    // prefetch first two Ws frags; latency hides under the sigmoid phase
    us8 s0n = *(const us8*)ps;
    us8 s1n = *(const us8*)(ps + 8192);

    // ---- sigmoid phase (NO barrier needed: rh is a separate buffer) ----
    float pst[4][4];
    const int rrow0 = (lane >> 4) * 4;
#pragma unroll
    for (int m = 0; m < 4; ++m) {
#pragma unroll
        for (int i = 0; i < 4; ++i) {
            int lrow = m * 16 + rrow0 + i;
            int cs = col ^ ((lrow & 7) << 3);
            float p = bf2f(sm[lrow * 512 + cs]);       // prev_h (bf16) from LDS
            float z = 1.f / (1.f + __expf(-(accz[m][i] + bzc)));
            float r = 1.f / (1.f + __expf(-(accr[m][i] + brc)));
            accz[m][i] = z;                            // keep z for epilogue
            pst[m][i]  = p;                            // keep p for epilogue
            rh[lrow * 256 + cs] = f2bf(r * p);         // rh to separate buffer
        }
    }
    __syncthreads();

    // ---- stage 2a: candidate GEMM, k in [0,256) from rh, depth-2 prefetch ----
    f32x4 accs[4] = {};
#pragma unroll 4
    for (int kt = 0; kt < 8; ++kt) {
        bf16x8 B = __builtin_bit_cast(bf16x8, s0n);
        s0n = s1n;
        s1n = *(const us8*)(ps + (size_t)(kt + 2) * 8192);
        int ak = kt * 32 + kg;
#pragma unroll
        for (int m = 0; m < 4; ++m) {
            int arow = m * 16 + l15;
            bf16x8 a = __builtin_bit_cast(bf16x8,
                *(const us8*)&rh[arow * 256 + (ak ^ ((arow & 7) << 3))]);
            accs[m] = __builtin_amdgcn_mfma_f32_16x16x32_bf16(a, B, accs[m], 0, 0, 0);
        }
    }
    // ---- stage 2b: k in [256,512) from the x half of sm ----
#pragma unroll 4
    for (int kt = 8; kt < 16; ++kt) {
        bf16x8 B = __builtin_bit_cast(bf16x8, s0n);
        s0n = s1n;
        if (kt < 14) s1n = *(const us8*)(ps + (size_t)(kt + 2) * 8192);
        int ak = kt * 32 + kg;                         // >= 256: x half, same swizzle
#pragma unroll
        for (int m = 0; m < 4; ++m) {
            int arow = m * 16 + l15;
            bf16x8 a = __builtin_bit_cast(bf16x8,
                *(const us8*)&sm[arow * 512 + (ak ^ ((arow & 7) << 3))]);
            accs[m] = __builtin_amdgcn_mfma_f32_16x16x32_bf16(a, B, accs[m], 0, 0, 0);
        }
    }

    // ---- epilogue: h' = (1-z)*p + z*tanh(s+bs) ----
#pragma unroll
    for (int m = 0; m < 4; ++m) {
#pragma unroll
        for (int i = 0; i < 4; ++i) {
            float s = accs[m][i] + bsc;
            float e = __expf(-2.f * fabsf(s));
            float th = (1.f - e) / (1.f + e);
            th = (s < 0.f) ? -th : th;
            float z = accz[m][i];
            float p = pst[m][i];
            int grow = brow + m * 16 + rrow0 + i;
            out[(size_t)grow * 256 + col] = (1.f - z) * p + z * th;
        }
    }
}

extern "C" void kernel_launch(void* const* d_in, const int* in_sizes, int n_in,
                              void* d_out, int out_size, void* d_ws, size_t ws_size,
                              hipStream_t stream) {
    const float* x  = (const float*)d_in[0];
    const float* ph = (const float*)d_in[1];
    const float* Wz = (const float*)d_in[2];
    const float* bz = (const float*)d_in[3];
    const float* Wr = (const float*)d_in[4];
    const float* br = (const float*)d_in[5];
    const float* Ws = (const float*)d_in[6];
    const float* bs = (const float*)d_in[7];
    unsigned short* Wp = (unsigned short*)d_ws;        // 786432 bytes used

    hipLaunchKernelGGL(pack_weights, dim3(1536), dim3(256), 0, stream, Wz, Wr, Ws, Wp);
    hipLaunchKernelGGL(gru_main, dim3(256), dim3(1024), 0, stream,
                       x, ph, bz, br, bs, Wp, (float*)d_out);
}

// Round 9
// 33.623 us; speedup vs baseline: 1.8837x; 1.0145x over previous
//
#include <hip/hip_runtime.h>
#include <hip/hip_bf16.h>

// GRU cell: B=16384, IN=256, UNITS=256, K = IN+UNITS = 512.
//   z = sigmoid([h,x]@Wz + bz); r = sigmoid([h,x]@Wr + br)
//   h~ = tanh([r*h, x]@Ws + bs);  h' = (1-z)*h + z*h~
// Round 9: K-split pipeline. Stage ph only, then x->regs under GEMM1a (kt0-7),
// ds_write x, GEMM1b (kt8-15). GEMM2 runs x-half first so the rh barrier has
// slack. Pack kernel now does 16B coalesced stores.

#define ROWS 64

typedef float f32x4 __attribute__((ext_vector_type(4)));
typedef __bf16 bf16x8 __attribute__((ext_vector_type(8)));
typedef unsigned short us8 __attribute__((ext_vector_type(8)));
typedef unsigned short us4v __attribute__((ext_vector_type(4)));

static __device__ __forceinline__ unsigned short f2bf(float f) {
    __bf16 h = (__bf16)f;                              // RNE, enables v_cvt_pk
    return __builtin_bit_cast(unsigned short, h);
}
static __device__ __forceinline__ float bf2f(unsigned short u) {
    union { unsigned u; float f; } v; v.u = ((unsigned)u) << 16;
    return v.f;
}

// Pack W[512][256] (fp32 row-major) -> [kt][nt][lane][8] bf16 frags.
// Thread = one fragment row: reads 8 fp32 (stride 256), writes 16B coalesced.
__global__ void pack_weights(const float* __restrict__ Wz,
                             const float* __restrict__ Wr,
                             const float* __restrict__ Ws,
                             unsigned short* __restrict__ out) {
    int gid = blockIdx.x * blockDim.x + threadIdx.x;   // 0 .. 49152
    int w    = gid >> 14;                              // 16384 frag-lanes per W
    int rem  = gid & 16383;
    int kt   = rem >> 10;
    int rem2 = rem & 1023;
    int nt   = rem2 >> 6;
    int lane = rem2 & 63;
    int hi = lane >> 4, lo = lane & 15;
    const float* W = (w == 0) ? Wz : (w == 1) ? Wr : Ws;
    const float* src = W + (size_t)(kt * 32 + hi * 8) * 256 + nt * 16 + lo;
    us8 o;
#pragma unroll
    for (int j = 0; j < 8; ++j) o[j] = f2bf(src[(size_t)j * 256]);
    *(us8*)&out[(size_t)w * 131072 + (size_t)(((kt * 16 + nt) * 64 + lane) * 8)] = o;
}

__launch_bounds__(1024, 4)
__global__ void gru_main(const float* __restrict__ x,
                         const float* __restrict__ ph,
                         const float* __restrict__ bz,
                         const float* __restrict__ br,
                         const float* __restrict__ bs,
                         const unsigned short* __restrict__ Wp,
                         float* __restrict__ out) {
    __shared__ unsigned short sm[ROWS * 512];          // 64 KiB: [ph | x], swizzled
    __shared__ unsigned short rh[ROWS * 256];          // 32 KiB: r*ph, swizzled

    const int tid  = threadIdx.x;
    const int lane = tid & 63;
    const int wid  = tid >> 6;                         // 0..15 = N-slice (nt)
    const int brow = blockIdx.x * ROWS;

    const int l15 = lane & 15;
    const int kg  = (lane >> 4) << 3;                  // k sub-offset 0,8,16,24
    const int col = wid * 16 + l15;

    const unsigned short* pz = Wp          + (size_t)((wid * 64 + lane) * 8);
    const unsigned short* pr = Wp + 131072 + (size_t)((wid * 64 + lane) * 8);
    const unsigned short* ps = Wp + 262144 + (size_t)((wid * 64 + lane) * 8);
    us8 b0n = *(const us8*)pz;                         // kt=0, flies during staging
    us8 b1n = *(const us8*)pr;
    float bzc = bz[col], brc = br[col], bsc = bs[col];

    // ---- stage ph -> k[0,256) as bf16, swizzled ----
#pragma unroll
    for (int it = 0; it < 4; ++it) {
        int i   = tid + it * 1024;                     // 4096 float4 total
        int row = i >> 6;
        int c4  = (i & 63) << 2;
        int swr = (row & 7) << 3;
        float4 a = *(const float4*)&ph[(size_t)(brow + row) * 256 + c4];
        us4v u; u.x = f2bf(a.x); u.y = f2bf(a.y); u.z = f2bf(a.z); u.w = f2bf(a.w);
        *(us4v*)&sm[row * 512 + (c4 ^ swr)] = u;
    }
    __syncthreads();                                   // bar1: ph staged

    // ---- x loads to regs: fly under GEMM1a ----
    float4 xr[4];
#pragma unroll
    for (int it = 0; it < 4; ++it) {
        int i   = tid + it * 1024;
        int row = i >> 6;
        int c4  = (i & 63) << 2;
        xr[it] = *(const float4*)&x[(size_t)(brow + row) * 256 + c4];
    }

    // ---- GEMM1a: z,r over ph half (kt 0..7), depth-1 B prefetch ----
    f32x4 accz[4] = {};
    f32x4 accr[4] = {};
#pragma unroll 4
    for (int kt = 0; kt < 8; ++kt) {
        bf16x8 B0 = __builtin_bit_cast(bf16x8, b0n);
        bf16x8 B1 = __builtin_bit_cast(bf16x8, b1n);
        b0n = *(const us8*)(pz + (size_t)(kt + 1) * 8192);
        b1n = *(const us8*)(pr + (size_t)(kt + 1) * 8192);
        int ak = kt * 32 + kg;
#pragma unroll
        for (int m = 0; m < 4; ++m) {
            int arow = m * 16 + l15;
            bf16x8 a = __builtin_bit_cast(bf16x8,
                *(const us8*)&sm[arow * 512 + (ak ^ ((arow & 7) << 3))]);
            accz[m] = __builtin_amdgcn_mfma_f32_16x16x32_bf16(a, B0, accz[m], 0, 0, 0);
            accr[m] = __builtin_amdgcn_mfma_f32_16x16x32_bf16(a, B1, accr[m], 0, 0, 0);
        }
    }

    // ---- write x (bf16) into k[256,512) ----
#pragma unroll
    for (int it = 0; it < 4; ++it) {
        int i   = tid + it * 1024;
        int row = i >> 6;
        int c4  = (i & 63) << 2;
        int swr = (row & 7) << 3;
        us4v v; v.x = f2bf(xr[it].x); v.y = f2bf(xr[it].y);
        v.z = f2bf(xr[it].z); v.w = f2bf(xr[it].w);
        *(us4v*)&sm[row * 512 + ((256 + c4) ^ swr)] = v;
    }
    __syncthreads();                                   // bar2: x staged

    // prefetch Ws kt=8,9 (consumed by GEMM2-x); fly under GEMM1b
    us8 s0n = *(const us8*)(ps + (size_t)8 * 8192);
    us8 s1n = *(const us8*)(ps + (size_t)9 * 8192);

    // ---- GEMM1b: z,r over x half (kt 8..15) ----
#pragma unroll 4
    for (int kt = 8; kt < 16; ++kt) {
        bf16x8 B0 = __builtin_bit_cast(bf16x8, b0n);
        bf16x8 B1 = __builtin_bit_cast(bf16x8, b1n);
        if (kt < 15) {
            b0n = *(const us8*)(pz + (size_t)(kt + 1) * 8192);
            b1n = *(const us8*)(pr + (size_t)(kt + 1) * 8192);
        }
        int ak = kt * 32 + kg;
#pragma unroll
        for (int m = 0; m < 4; ++m) {
            int arow = m * 16 + l15;
            bf16x8 a = __builtin_bit_cast(bf16x8,
                *(const us8*)&sm[arow * 512 + (ak ^ ((arow & 7) << 3))]);
            accz[m] = __builtin_amdgcn_mfma_f32_16x16x32_bf16(a, B0, accz[m], 0, 0, 0);
            accr[m] = __builtin_amdgcn_mfma_f32_16x16x32_bf16(a, B1, accr[m], 0, 0, 0);
        }
    }

    // ---- sigmoid; rh -> separate buffer; stash p,z ----
    float pst[4][4];
    const int rrow0 = (lane >> 4) * 4;
#pragma unroll
    for (int m = 0; m < 4; ++m) {
#pragma unroll
        for (int i = 0; i < 4; ++i) {
            int lrow = m * 16 + rrow0 + i;
            int cs = col ^ ((lrow & 7) << 3);
            float p = bf2f(sm[lrow * 512 + cs]);
            float z = 1.f / (1.f + __expf(-(accz[m][i] + bzc)));
            float r = 1.f / (1.f + __expf(-(accr[m][i] + brc)));
            accz[m][i] = z;
            pst[m][i]  = p;
            rh[lrow * 256 + cs] = f2bf(r * p);
        }
    }

    // ---- GEMM2-x: kt 8..15 from sm x-half (stable since bar2, no barrier) ----
    f32x4 accs[4] = {};
#pragma unroll 4
    for (int kt = 8; kt < 16; ++kt) {
        bf16x8 B = __builtin_bit_cast(bf16x8, s0n);
        s0n = s1n;
        s1n = *(const us8*)(ps + (size_t)((kt + 2) & 15) * 8192);
        int ak = kt * 32 + kg;
#pragma unroll
        for (int m = 0; m < 4; ++m) {
            int arow = m * 16 + l15;
            bf16x8 a = __builtin_bit_cast(bf16x8,
                *(const us8*)&sm[arow * 512 + (ak ^ ((arow & 7) << 3))]);
            accs[m] = __builtin_amdgcn_mfma_f32_16x16x32_bf16(a, B, accs[m], 0, 0, 0);
        }
    }
    __syncthreads();                                   // bar3: rh ready

    // ---- GEMM2-rh: kt 0..7 from rh ----
#pragma unroll 4
    for (int kt = 0; kt < 8; ++kt) {
        bf16x8 B = __builtin_bit_cast(bf16x8, s0n);
        s0n = s1n;
        if (kt < 6) s1n = *(const us8*)(ps + (size_t)(kt + 2) * 8192);
        int ak = kt * 32 + kg;
#pragma unroll
        for (int m = 0; m < 4; ++m) {
            int arow = m * 16 + l15;
            bf16x8 a = __builtin_bit_cast(bf16x8,
                *(const us8*)&rh[arow * 256 + (ak ^ ((arow & 7) << 3))]);
            accs[m] = __builtin_amdgcn_mfma_f32_16x16x32_bf16(a, B, accs[m], 0, 0, 0);
        }
    }

    // ---- epilogue: h' = (1-z)*p + z*tanh(s+bs) ----
#pragma unroll
    for (int m = 0; m < 4; ++m) {
#pragma unroll
        for (int i = 0; i < 4; ++i) {
            float s = accs[m][i] + bsc;
            float e = __expf(-2.f * fabsf(s));
            float th = (1.f - e) / (1.f + e);
            th = (s < 0.f) ? -th : th;
            float z = accz[m][i];
            float p = pst[m][i];
            int grow = brow + m * 16 + rrow0 + i;
            out[(size_t)grow * 256 + col] = (1.f - z) * p + z * th;
        }
    }
}

extern "C" void kernel_launch(void* const* d_in, const int* in_sizes, int n_in,
                              void* d_out, int out_size, void* d_ws, size_t ws_size,
                              hipStream_t stream) {
    const float* x  = (const float*)d_in[0];
    const float* ph = (const float*)d_in[1];
    const float* Wz = (const float*)d_in[2];
    const float* bz = (const float*)d_in[3];
    const float* Wr = (const float*)d_in[4];
    const float* br = (const float*)d_in[5];
    const float* Ws = (const float*)d_in[6];
    const float* bs = (const float*)d_in[7];
    unsigned short* Wp = (unsigned short*)d_ws;        // 786432 bytes used

    hipLaunchKernelGGL(pack_weights, dim3(192), dim3(256), 0, stream, Wz, Wr, Ws, Wp);
    hipLaunchKernelGGL(gru_main, dim3(256), dim3(1024), 0, stream,
                       x, ph, bz, br, bs, Wp, (float*)d_out);
}